// Round 7
// baseline (125.905 us; speedup 1.0000x reference)
//
#include <hip/hip_runtime.h>
#include <cfloat>
#include <cstdint>

// Problem constants (SHAPE=(96,128,128), B=2, C=32, two maxpool(K3,S2,P1) layers)
// Composed pooling: window 7, stride 4, pad 3. Output grid 2 x 24 x 32 x 32 x 32.
#define B_    2
#define OD    24
#define OH    32
#define OW    32
#define NC    32
#define NBINS (B_ * OD * OH * OW)   // 49152 (fallback path only)
#define SCAN_T 1024
#define CHUNK  (NBINS / SCAN_T)

// tile geometry: 4 x 4 x 4 output cells per workgroup
#define TZ 4
#define TY 4
#define TX 4
#define TCELLS (TZ*TY*TX)           // 64
#define NTZ (OD/TZ)                 // 6
#define NTY (OH/TY)                 // 8
#define NTX (OW/TX)                 // 8
#define NTILES (B_*NTZ*NTY*NTX)     // 768
#define CAP2  1024                  // entries per tile list (avg ~436)
#define OVF2  65536

// ---------------- monotone float<->uint transform ----------------
// order-preserving for non-NaN floats; 0 == "never touched" (xform(f)>0 for all finite f)
__device__ __forceinline__ unsigned xform(float f) {
    unsigned u = __float_as_uint(f);
    return u ^ ((unsigned)((int)u >> 31) | 0x80000000u);
}
__device__ __forceinline__ float unxform(unsigned t) {
    return (t == 0u) ? 0.0f
           : __uint_as_float((t >> 31) ? (t ^ 0x80000000u) : ~t);
}

// ---------------- fast path ----------------
// ws: cursor[NTILES] | ovf_n[8] | lists[NTILES*CAP2] int2 | ovf[OVF2] int4

__global__ __launch_bounds__(256) void k_bin(const int* __restrict__ coors,
                                             int* __restrict__ cursor,
                                             int2* __restrict__ lists,
                                             int* __restrict__ ovf_n,
                                             int4* __restrict__ ovf, int N) {
    int i = blockIdx.x * blockDim.x + threadIdx.x;
    if (i >= N) return;
    int4 cc = reinterpret_cast<const int4*>(coors)[i];   // b, z, y, x
    const int b = cc.x;
    const int bz = cc.y >> 2, by = cc.z >> 2, bx = cc.w >> 2;
    // mask bit k (k = lz + 2*ly + 4*lx): point contributes to cell (bz+lz, by+ly, bx+lx)
    int mask = 0xFF;
    if (!(cc.y & 3) || bz + 1 >= OD) mask &= 0x55;
    if (!(cc.z & 3) || by + 1 >= OH) mask &= 0x33;
    if (!(cc.w & 3) || bx + 1 >= OW) mask &= 0x0F;

    // per-axis primary tile + submask; secondary tile iff the +1 cell crosses
    const int tzA = bz >> 2;  const bool zB = (mask & 0xAA) && ((bz & 3) == 3);
    const int szA = 0x55 | (((bz & 3) == 3) ? 0 : 0xAA);
    const int tyA = by >> 2;  const bool yB = (mask & 0xCC) && ((by & 3) == 3);
    const int syA = 0x33 | (((by & 3) == 3) ? 0 : 0xCC);
    const int txA = bx >> 2;  const bool xB = (mask & 0xF0) && ((bx & 3) == 3);
    const int sxA = 0x0F | (((bx & 3) == 3) ? 0 : 0xF0);

    const int rec = i << 8;
    for (int az = 0; az <= (int)zB; ++az) {
        const int tz = tzA + az, sz = az ? 0xAA : szA;
        for (int ay = 0; ay <= (int)yB; ++ay) {
            const int ty = tyA + ay, sy = ay ? 0xCC : syA;
            for (int ax = 0; ax <= (int)xB; ++ax) {
                const int tx = txA + ax, sx = ax ? 0xF0 : sxA;
                const int fm = mask & sz & sy & sx;
                if (!fm) continue;
                const int t  = ((b * NTZ + tz) * NTY + ty) * NTX + tx;
                const int cb = (bz - tz * TZ) * (TY * TX) + (by - ty * TY) * TX
                             + (bx - tx * TX);
                int pos = atomicAdd(&cursor[t], 1);
                if (pos < CAP2) {
                    lists[t * CAP2 + pos] = make_int2(rec | fm, cb);
                } else {
                    int o = atomicAdd(ovf_n, 1);
                    if (o < OVF2) ovf[o] = make_int4(t, rec | fm, cb, 0);
                }
            }
        }
    }
}

// one block per tile; thread = (slot s = tid>>5 of 16, channel c = tid&31)
__global__ __launch_bounds__(512) void k_tile(const float* __restrict__ feat,
                                              const int* __restrict__ cursor,
                                              const int2* __restrict__ lists,
                                              const int* __restrict__ ovf_n,
                                              const int4* __restrict__ ovf,
                                              float4* __restrict__ out4) {
    __shared__ unsigned sm_out[TCELLS * NC];   // 64 cells x 32 ch = 8 KB

    const int t   = blockIdx.x;
    const int tid = threadIdx.x;
    const int tx_ = t & (NTX - 1);
    const int ty_ = (t >> 3) & (NTY - 1);
    const int rest = t >> 6;                  // 0..11
    const int b   = (rest >= NTZ) ? 1 : 0;
    const int tz_ = rest - b * NTZ;

    for (int v = tid; v < TCELLS * NC; v += 512) sm_out[v] = 0u;
    __syncthreads();

    int cnt = cursor[t]; if (cnt > CAP2) cnt = CAP2;
    const int2* L = lists + (size_t)t * CAP2;
    const int s = tid >> 5;
    const int c = tid & 31;

    // main loop: 16 slots x 4-deep ILP = 64 entries per round
    for (int j0 = s; j0 < cnt; j0 += 64) {
        int2 e[4];
#pragma unroll
        for (int u = 0; u < 4; ++u) {
            int j = j0 + 16 * u;
            e[u] = (j < cnt) ? L[j] : make_int2(0, 0);   // fm=0 -> no-op
        }
        unsigned tv[4];
#pragma unroll
        for (int u = 0; u < 4; ++u) {
            float f = feat[(((unsigned)e[u].x) >> 8) * NC + c];
            tv[u] = xform(f);
        }
#pragma unroll
        for (int u = 0; u < 4; ++u) {
            const int fm   = e[u].x & 0xFF;
            const int base = e[u].y * NC + c;
#pragma unroll
            for (int k = 0; k < 8; ++k) {
                const int koff = ((k & 1) * (TY * TX) + ((k >> 1) & 1) * TX
                               + ((k >> 2) & 1)) * NC;
                if ((fm >> k) & 1) atomicMax(&sm_out[base + koff], tv[u]);
            }
        }
    }

    // overflow net (expected empty)
    int on = *ovf_n;
    if (on > 0 && s == 0) {
        if (on > OVF2) on = OVF2;
        for (int j = 0; j < on; ++j) {
            int4 e = ovf[j];
            if (e.x != t) continue;
            unsigned tvv = xform(feat[(((unsigned)e.y) >> 8) * NC + c]);
            const int fm = e.y & 0xFF, base = e.z * NC + c;
#pragma unroll
            for (int k = 0; k < 8; ++k) {
                const int koff = ((k & 1) * (TY * TX) + ((k >> 1) & 1) * TX
                               + ((k >> 2) & 1)) * NC;
                if ((fm >> k) & 1) atomicMax(&sm_out[base + koff], tvv);
            }
        }
    }
    __syncthreads();

    // epilogue: 64 cells x 8 float4 = 512 stores, one per thread, coalesced
    {
        const int cell = tid >> 3, quad = tid & 7;
        const int i = cell >> 4, jj = (cell >> 2) & 3, l = cell & 3;
        uint4 uv = *(const uint4*)&sm_out[cell * NC + quad * 4];
        float4 o;
        o.x = unxform(uv.x); o.y = unxform(uv.y);
        o.z = unxform(uv.z); o.w = unxform(uv.w);
        out4[(((size_t)(b * OD + tz_ * TZ + i) * OH + (ty_ * TY + jj)) * OW
              + (tx_ * TX + l)) * (NC / 4) + quad] = o;
    }
}

// ================= fallback path (scan-based, small ws) =====================

__global__ void k_hist(const int* __restrict__ coors, int* __restrict__ counts, int N) {
    int i = blockIdx.x * blockDim.x + threadIdx.x;
    if (i >= N) return;
    int4 cc = reinterpret_cast<const int4*>(coors)[i];
    int bin = (((cc.x * OD + (cc.y >> 2)) * OH + (cc.z >> 2)) * OW + (cc.w >> 2));
    atomicAdd(&counts[bin], 1);
}

__global__ void k_scan(const int* __restrict__ counts,
                       int2* __restrict__ binfo,
                       int* __restrict__ cursor) {
    __shared__ int lds[SCAN_T];
    int t = threadIdx.x;
    int base = t * CHUNK;
    int s = 0;
#pragma unroll
    for (int k = 0; k < CHUNK; ++k) s += counts[base + k];
    lds[t] = s;
    __syncthreads();
    for (int d = 1; d < SCAN_T; d <<= 1) {
        int v = (t >= d) ? lds[t - d] : 0;
        __syncthreads();
        lds[t] += v;
        __syncthreads();
    }
    int excl = (t == 0) ? 0 : lds[t - 1];
    for (int k = 0; k < CHUNK; ++k) {
        int i = base + k;
        int c = counts[i];
        binfo[i] = make_int2(excl, c);
        cursor[i] = excl;
        excl += c;
    }
}

__global__ void k_place(const int* __restrict__ coors, int* __restrict__ cursor,
                        int* __restrict__ records, int N) {
    int i = blockIdx.x * blockDim.x + threadIdx.x;
    if (i >= N) return;
    int4 cc = reinterpret_cast<const int4*>(coors)[i];
    int bin = (((cc.x * OD + (cc.y >> 2)) * OH + (cc.z >> 2)) * OW + (cc.w >> 2));
    int pos = atomicAdd(&cursor[bin], 1);
    records[pos] = (i << 6) | (cc.y & 3) | ((cc.z & 3) << 2) | ((cc.w & 3) << 4);
}

__global__ __launch_bounds__(256) void k_gather_fb(const float4* __restrict__ feat4,
                                                   const int2* __restrict__ binfo,
                                                   const int* __restrict__ records,
                                                   float4* __restrict__ out4, int N) {
    int tid  = blockIdx.x * blockDim.x + threadIdx.x;
    int wid  = tid >> 6;
    int lane = threadIdx.x & 63;
    int q    = lane >> 3;
    int cq   = lane & 7;

    int ox  = wid & (OW - 1);
    int oy  = (wid >> 5) & (OH - 1);
    int bzc = wid >> 10;
    int b   = (bzc >= OD) ? 1 : 0;
    int oz  = bzc - b * OD;

    int2 bi[8];
#pragma unroll
    for (int k = 0; k < 8; ++k) {
        const int lz = k & 1, ly = (k >> 1) & 1, lx = (k >> 2) & 1;
        int z2 = oz - lz, y2 = oy - ly, x2 = ox - lx;
        bool okbin = ((z2 | y2 | x2) >= 0);
        int bin = ((b * OD + z2) * OH + y2) * OW + x2;
        int2 v = binfo[okbin ? bin : 0];
        if (!okbin) { v.x = N; v.y = 0; }
        bi[k] = v;
    }

    int recs[8];
#pragma unroll
    for (int k = 0; k < 8; ++k) {
        int j = (q < bi[k].y) ? q : 0;
        recs[k] = records[bi[k].x + j];
    }

    float4 m = make_float4(-FLT_MAX, -FLT_MAX, -FLT_MAX, -FLT_MAX);
    int any = 0;
#pragma unroll
    for (int k = 0; k < 8; ++k) {
        int rec = recs[k];
        bool ok = (q < bi[k].y);
        if (k & 1) ok = ok && ((rec & 3)  != 0);
        if (k & 2) ok = ok && ((rec & 12) != 0);
        if (k & 4) ok = ok && ((rec & 48) != 0);
        if (ok) {
            float4 f = feat4[(rec >> 6) * (NC / 4) + cq];
            m.x = fmaxf(m.x, f.x); m.y = fmaxf(m.y, f.y);
            m.z = fmaxf(m.z, f.z); m.w = fmaxf(m.w, f.w);
            any = 1;
        }
    }

#pragma unroll
    for (int k = 0; k < 8; ++k) {
        for (int j0 = 8; j0 < bi[k].y; j0 += 8) {
            int j = j0 + q;
            bool ok = (j < bi[k].y);
            int rec = records[bi[k].x + (ok ? j : 0)];
            if (k & 1) ok = ok && ((rec & 3)  != 0);
            if (k & 2) ok = ok && ((rec & 12) != 0);
            if (k & 4) ok = ok && ((rec & 48) != 0);
            if (ok) {
                float4 f = feat4[(rec >> 6) * (NC / 4) + cq];
                m.x = fmaxf(m.x, f.x); m.y = fmaxf(m.y, f.y);
                m.z = fmaxf(m.z, f.z); m.w = fmaxf(m.w, f.w);
                any = 1;
            }
        }
    }

#pragma unroll
    for (int s = 8; s < 64; s <<= 1) {
        m.x = fmaxf(m.x, __shfl_xor(m.x, s, 64));
        m.y = fmaxf(m.y, __shfl_xor(m.y, s, 64));
        m.z = fmaxf(m.z, __shfl_xor(m.z, s, 64));
        m.w = fmaxf(m.w, __shfl_xor(m.w, s, 64));
    }
    bool active = (__ballot(any) != 0ULL);

    if (q == 0) {
        float4 z4 = make_float4(0.f, 0.f, 0.f, 0.f);
        out4[wid * (NC / 4) + cq] = active ? m : z4;
    }
}

// ---------------- launch ----------------

extern "C" void kernel_launch(void* const* d_in, const int* in_sizes, int n_in,
                              void* d_out, int out_size, void* d_ws, size_t ws_size,
                              hipStream_t stream) {
    const float* feat  = (const float*)d_in[0];
    const int*   coors = (const int*)d_in[1];
    const int N = in_sizes[0] / NC;          // 200000
    float* out = (float*)d_out;              // 1572864 floats

    const size_t fast_ints = (size_t)NTILES + 8 + (size_t)NTILES * CAP2 * 2
                           + (size_t)OVF2 * 4;
    if (ws_size >= fast_ints * sizeof(int)) {
        int*  cursor = (int*)d_ws;                         // NTILES
        int*  ovf_n  = cursor + NTILES;                    // 1 (+7 pad)
        int2* lists  = (int2*)(ovf_n + 8);                 // NTILES*CAP2
        int4* ovf    = (int4*)(lists + (size_t)NTILES * CAP2);

        hipMemsetAsync(cursor, 0, (NTILES + 8) * sizeof(int), stream);
        k_bin<<<(N + 255) / 256, 256, 0, stream>>>(coors, cursor, lists, ovf_n, ovf, N);
        k_tile<<<NTILES, 512, 0, stream>>>(feat, cursor, (const int2*)lists,
                                           ovf_n, (const int4*)ovf, (float4*)out);
    } else {
        // fallback: scan-based path, ~1.6 MB ws
        int*  counts  = (int*)d_ws;
        int2* binfo   = (int2*)(counts + NBINS);
        int*  cursor  = (int*)(binfo + NBINS);
        int*  records = cursor + NBINS;

        hipMemsetAsync(counts, 0, NBINS * sizeof(int), stream);
        k_hist <<<(N + 255) / 256, 256, 0, stream>>>(coors, counts, N);
        k_scan <<<1, SCAN_T, 0, stream>>>(counts, binfo, cursor);
        k_place<<<(N + 255) / 256, 256, 0, stream>>>(coors, cursor, records, N);
        k_gather_fb<<<(NBINS * 64) / 256, 256, 0, stream>>>(
            (const float4*)feat, (const int2*)binfo, records, (float4*)out, N);
    }
}

// Round 8
// 43.512 us; speedup vs baseline: 2.8936x; 2.8936x over previous
//
#include <hip/hip_runtime.h>
#include <cfloat>
#include <cstdint>

// Problem constants (SHAPE=(96,128,128), B=2, C=32, two maxpool(K3,S2,P1) layers)
// Composed pooling: window 7, stride 4, pad 3. Output grid 2 x 24 x 32 x 32 x 32.
#define B_    2
#define OD    24
#define OH    32
#define OW    32
#define NC    32
#define NBINS (B_ * OD * OH * OW)   // 49152
#define LINE  16                    // ints per bin line: [count, rec0..rec14]
#define CAPR  15
#define OVF_CAP 100000
#define SCAN_T 1024
#define CHUNK  (NBINS / SCAN_T)

// tile geometry: 4 x 4 x 4 output cells per workgroup
#define TZ 4
#define TY 4
#define TX 4
#define TCELLS (TZ*TY*TX)           // 64
#define NTZ (OD/TZ)                 // 6
#define NTY (OH/TY)                 // 8
#define NTX (OW/TX)                 // 8
#define NTILES (B_*NTZ*NTY*NTX)     // 768 = 3 blocks/CU exactly
#define NBZ (TZ+1)
#define NBY (TY+1)
#define NBX (TX+1)
#define NB  (NBZ*NBY*NBX)           // 125 bins per tile neighborhood
#define LIST_CAP 1792               // avg entries/tile ~437

// ---------------- monotone float<->uint transform ----------------
// order-preserving for non-NaN floats; 0 == "never touched" (xform(f)>0 for all finite f)
__device__ __forceinline__ unsigned xform(float f) {
    unsigned u = __float_as_uint(f);
    return u ^ ((unsigned)((int)u >> 31) | 0x80000000u);
}
__device__ __forceinline__ float unxform(unsigned t) {
    return (t == 0u) ? 0.0f
           : __uint_as_float((t >> 31) ? (t ^ 0x80000000u) : ~t);
}

// ---------------- prologue (round-6 proven: 49152-address contention) -------

__global__ void k_zero(int* __restrict__ lines, int* __restrict__ ovf_n) {
    int i = blockIdx.x * blockDim.x + threadIdx.x;
    if (i < NBINS) lines[i * LINE] = 0;
    if (i == 0) *ovf_n = 0;
}

__global__ __launch_bounds__(256) void k_bin(const int* __restrict__ coors,
                                             int* __restrict__ lines,
                                             int* __restrict__ ovf_n,
                                             int2* __restrict__ ovf, int N) {
    int i = blockIdx.x * blockDim.x + threadIdx.x;
    if (i >= N) return;
    int4 cc = reinterpret_cast<const int4*>(coors)[i];   // b, z, y, x
    int bin = (((cc.x * OD + (cc.y >> 2)) * OH + (cc.z >> 2)) * OW + (cc.w >> 2));
    // bit k (k = lz + 2*ly + 4*lx): point qualifies for cell bin+(lz,ly,lx)
    int mask = 0xFF;
    if (!(cc.y & 3)) mask &= 0x55;
    if (!(cc.z & 3)) mask &= 0x33;
    if (!(cc.w & 3)) mask &= 0x0F;
    int rec = (i << 8) | mask;   // mask bit0 always set -> rec != 0
    int pos = atomicAdd(&lines[bin * LINE], 1);
    if (pos < CAPR) {
        lines[bin * LINE + 1 + pos] = rec;
    } else {
        int o = atomicAdd(ovf_n, 1);
        if (o < OVF_CAP) ovf[o] = make_int2(bin, rec);
    }
}

// ---------------- tile gather-scatter ----------------
// one block per 4x4x4-cell tile; thread = (slot s = tid>>5 of 16, channel c = tid&31)

__global__ __launch_bounds__(512) void k_tile(const float* __restrict__ feat,
                                              const int* __restrict__ lines,
                                              const int* __restrict__ ovf_n,
                                              const int2* __restrict__ ovf,
                                              float4* __restrict__ out4) {
    __shared__ unsigned sm_out[TCELLS * NC];   // 8 KB
    __shared__ int2 list[LIST_CAP];            // 14 KB
    __shared__ int sm_cursor;

    const int t   = blockIdx.x;
    const int tid = threadIdx.x;
    const int tx_ = t & (NTX - 1);
    const int ty_ = (t >> 3) & (NTY - 1);
    const int rest = t >> 6;                   // b*NTZ + tz, 0..11
    const int b   = (rest >= NTZ) ? 1 : 0;
    const int tz_ = rest - b * NTZ;
    const int tz0 = tz_ * TZ, ty0 = ty_ * TY, tx0 = tx_ * TX;

    if (tid == 0) sm_cursor = 0;
    for (int v = tid; v < TCELLS * NC; v += 512) sm_out[v] = 0u;
    __syncthreads();

    // ---- build compact entry list: one thread per neighborhood bin ----
    if (tid < NB) {
        int rz  = tid / (NBY * NBX);
        int rem = tid - rz * (NBY * NBX);
        int ry  = rem / NBX;
        int rx  = rem - ry * NBX;
        int bz = tz0 - 1 + rz, by = ty0 - 1 + ry, bx = tx0 - 1 + rx;
        if ((bz | by | bx) >= 0) {             // upper side in-grid by tiling
            int bin = ((b * OD + bz) * OH + by) * OW + bx;
            const int4* lp = (const int4*)(lines + bin * LINE);
            int4 q0 = lp[0], q1 = lp[1], q2 = lp[2], q3 = lp[3];
            int rbuf[16];
            *(int4*)&rbuf[0]  = q0; *(int4*)&rbuf[4]  = q1;
            *(int4*)&rbuf[8]  = q2; *(int4*)&rbuf[12] = q3;
            int cnt = rbuf[0]; if (cnt > CAPR) cnt = CAPR;
            int bi = rz - 1, bj = ry - 1, bl = rx - 1;
            int vm = 0xFF;                     // tile-validity mask per k
            if (bi < 0) vm &= 0xAA;  if (bi > TZ - 2) vm &= 0x55;
            if (bj < 0) vm &= 0xCC;  if (bj > TY - 2) vm &= 0x33;
            if (bl < 0) vm &= 0xF0;  if (bl > TX - 2) vm &= 0x0F;
            int cb = bi * (TY * TX) + bj * TX + bl;
            // pass 1: count survivors (no private arrays -> no scratch)
            int nk = 0;
#pragma unroll
            for (int rs = 0; rs < CAPR; ++rs)
                if (rs < cnt && (rbuf[rs + 1] & vm & 0xFF)) ++nk;
            int pos = atomicAdd(&sm_cursor, nk);
            // pass 2: write
#pragma unroll
            for (int rs = 0; rs < CAPR; ++rs) {
                if (rs < cnt) {
                    int rec = rbuf[rs + 1];
                    int fm = rec & vm & 0xFF;
                    if (fm) {
                        if (pos < LIST_CAP) {
                            list[pos] = make_int2((rec & ~0xFF) | fm, cb);
                        } else {
                            // never-taken slow path: apply directly
                            unsigned idx = ((unsigned)rec) >> 8;
                            for (int c2 = 0; c2 < NC; ++c2) {
                                unsigned tvv = xform(feat[idx * NC + c2]);
#pragma unroll
                                for (int k = 0; k < 8; ++k) {
                                    const int koff = ((k & 1) * (TY * TX)
                                        + ((k >> 1) & 1) * TX + ((k >> 2) & 1)) * NC;
                                    if ((fm >> k) & 1)
                                        atomicMax(&sm_out[(cb * NC) + koff + c2], tvv);
                                }
                            }
                        }
                        ++pos;
                    }
                }
            }
        }
    }

    // ---- overflow net (expected empty) ----
    int on = *ovf_n;
    if (on > 0 && tid == 0) {
        if (on > OVF_CAP) on = OVF_CAP;
        for (int e = 0; e < on; ++e) {
            int2 ov = ovf[e];
            int bx = ov.x & (OW - 1);
            int by = (ov.x >> 5) & (OH - 1);
            int rest2 = ov.x >> 10;            // b*OD + bz
            int bb = (rest2 >= OD) ? 1 : 0;
            int bz = rest2 - bb * OD;
            if (bb != b) continue;
            int rz = bz - (tz0 - 1), ry = by - (ty0 - 1), rx = bx - (tx0 - 1);
            if (rz < 0 || rz >= NBZ || ry < 0 || ry >= NBY || rx < 0 || rx >= NBX) continue;
            int bi = rz - 1, bj = ry - 1, bl = rx - 1;
            int vm = 0xFF;
            if (bi < 0) vm &= 0xAA;  if (bi > TZ - 2) vm &= 0x55;
            if (bj < 0) vm &= 0xCC;  if (bj > TY - 2) vm &= 0x33;
            if (bl < 0) vm &= 0xF0;  if (bl > TX - 2) vm &= 0x0F;
            int fm = ov.y & vm & 0xFF;
            if (fm) {
                int pos = atomicAdd(&sm_cursor, 1);
                if (pos < LIST_CAP)
                    list[pos] = make_int2((ov.y & ~0xFF) | fm,
                                          bi * (TY * TX) + bj * TX + bl);
            }
        }
    }
    __syncthreads();
    int total = sm_cursor; if (total > LIST_CAP) total = LIST_CAP;

    // ---- main loop: 16 slots x 4-deep ILP = 64 entries per round ----
    const int s = tid >> 5;
    const int c = tid & 31;

    for (int j0 = s; j0 < total; j0 += 64) {
        int2 e0 = (j0      < total) ? list[j0]      : make_int2(0, 0);
        int2 e1 = (j0 + 16 < total) ? list[j0 + 16] : make_int2(0, 0);
        int2 e2 = (j0 + 32 < total) ? list[j0 + 32] : make_int2(0, 0);
        int2 e3 = (j0 + 48 < total) ? list[j0 + 48] : make_int2(0, 0);
        unsigned t0 = xform(feat[(((unsigned)e0.x) >> 8) * NC + c]);
        unsigned t1 = xform(feat[(((unsigned)e1.x) >> 8) * NC + c]);
        unsigned t2 = xform(feat[(((unsigned)e2.x) >> 8) * NC + c]);
        unsigned t3 = xform(feat[(((unsigned)e3.x) >> 8) * NC + c]);
#pragma unroll
        for (int k = 0; k < 8; ++k) {
            const int koff = ((k & 1) * (TY * TX) + ((k >> 1) & 1) * TX
                           + ((k >> 2) & 1)) * NC + c;
            if ((e0.x >> k) & 1) atomicMax(&sm_out[e0.y * NC + koff], t0);
            if ((e1.x >> k) & 1) atomicMax(&sm_out[e1.y * NC + koff], t1);
            if ((e2.x >> k) & 1) atomicMax(&sm_out[e2.y * NC + koff], t2);
            if ((e3.x >> k) & 1) atomicMax(&sm_out[e3.y * NC + koff], t3);
        }
    }
    __syncthreads();

    // ---- epilogue: 64 cells x 8 float4 = 512 stores, one per thread ----
    {
        const int cell = tid >> 3, quad = tid & 7;
        const int i = cell >> 4, jj = (cell >> 2) & 3, l = cell & 3;
        uint4 uv = *(const uint4*)&sm_out[cell * NC + quad * 4];
        float4 o;
        o.x = unxform(uv.x); o.y = unxform(uv.y);
        o.z = unxform(uv.z); o.w = unxform(uv.w);
        out4[(((size_t)(b * OD + tz0 + i) * OH + (ty0 + jj)) * OW
              + (tx0 + l)) * (NC / 4) + quad] = o;
    }
}

// ================= fallback path (scan-based, small ws) =====================

__global__ void k_hist(const int* __restrict__ coors, int* __restrict__ counts, int N) {
    int i = blockIdx.x * blockDim.x + threadIdx.x;
    if (i >= N) return;
    int4 cc = reinterpret_cast<const int4*>(coors)[i];
    int bin = (((cc.x * OD + (cc.y >> 2)) * OH + (cc.z >> 2)) * OW + (cc.w >> 2));
    atomicAdd(&counts[bin], 1);
}

__global__ void k_scan(const int* __restrict__ counts,
                       int2* __restrict__ binfo,
                       int* __restrict__ cursor) {
    __shared__ int lds[SCAN_T];
    int t = threadIdx.x;
    int base = t * CHUNK;
    int s = 0;
#pragma unroll
    for (int k = 0; k < CHUNK; ++k) s += counts[base + k];
    lds[t] = s;
    __syncthreads();
    for (int d = 1; d < SCAN_T; d <<= 1) {
        int v = (t >= d) ? lds[t - d] : 0;
        __syncthreads();
        lds[t] += v;
        __syncthreads();
    }
    int excl = (t == 0) ? 0 : lds[t - 1];
    for (int k = 0; k < CHUNK; ++k) {
        int i = base + k;
        int c = counts[i];
        binfo[i] = make_int2(excl, c);
        cursor[i] = excl;
        excl += c;
    }
}

__global__ void k_place(const int* __restrict__ coors, int* __restrict__ cursor,
                        int* __restrict__ records, int N) {
    int i = blockIdx.x * blockDim.x + threadIdx.x;
    if (i >= N) return;
    int4 cc = reinterpret_cast<const int4*>(coors)[i];
    int bin = (((cc.x * OD + (cc.y >> 2)) * OH + (cc.z >> 2)) * OW + (cc.w >> 2));
    int pos = atomicAdd(&cursor[bin], 1);
    records[pos] = (i << 6) | (cc.y & 3) | ((cc.z & 3) << 2) | ((cc.w & 3) << 4);
}

__global__ __launch_bounds__(256) void k_gather_fb(const float4* __restrict__ feat4,
                                                   const int2* __restrict__ binfo,
                                                   const int* __restrict__ records,
                                                   float4* __restrict__ out4, int N) {
    int tid  = blockIdx.x * blockDim.x + threadIdx.x;
    int wid  = tid >> 6;
    int lane = threadIdx.x & 63;
    int q    = lane >> 3;
    int cq   = lane & 7;

    int ox  = wid & (OW - 1);
    int oy  = (wid >> 5) & (OH - 1);
    int bzc = wid >> 10;
    int b   = (bzc >= OD) ? 1 : 0;
    int oz  = bzc - b * OD;

    int2 bi[8];
#pragma unroll
    for (int k = 0; k < 8; ++k) {
        const int lz = k & 1, ly = (k >> 1) & 1, lx = (k >> 2) & 1;
        int z2 = oz - lz, y2 = oy - ly, x2 = ox - lx;
        bool okbin = ((z2 | y2 | x2) >= 0);
        int bin = ((b * OD + z2) * OH + y2) * OW + x2;
        int2 v = binfo[okbin ? bin : 0];
        if (!okbin) { v.x = N; v.y = 0; }
        bi[k] = v;
    }

    int recs[8];
#pragma unroll
    for (int k = 0; k < 8; ++k) {
        int j = (q < bi[k].y) ? q : 0;
        recs[k] = records[bi[k].x + j];
    }

    float4 m = make_float4(-FLT_MAX, -FLT_MAX, -FLT_MAX, -FLT_MAX);
    int any = 0;
#pragma unroll
    for (int k = 0; k < 8; ++k) {
        int rec = recs[k];
        bool ok = (q < bi[k].y);
        if (k & 1) ok = ok && ((rec & 3)  != 0);
        if (k & 2) ok = ok && ((rec & 12) != 0);
        if (k & 4) ok = ok && ((rec & 48) != 0);
        if (ok) {
            float4 f = feat4[(rec >> 6) * (NC / 4) + cq];
            m.x = fmaxf(m.x, f.x); m.y = fmaxf(m.y, f.y);
            m.z = fmaxf(m.z, f.z); m.w = fmaxf(m.w, f.w);
            any = 1;
        }
    }

#pragma unroll
    for (int k = 0; k < 8; ++k) {
        for (int j0 = 8; j0 < bi[k].y; j0 += 8) {
            int j = j0 + q;
            bool ok = (j < bi[k].y);
            int rec = records[bi[k].x + (ok ? j : 0)];
            if (k & 1) ok = ok && ((rec & 3)  != 0);
            if (k & 2) ok = ok && ((rec & 12) != 0);
            if (k & 4) ok = ok && ((rec & 48) != 0);
            if (ok) {
                float4 f = feat4[(rec >> 6) * (NC / 4) + cq];
                m.x = fmaxf(m.x, f.x); m.y = fmaxf(m.y, f.y);
                m.z = fmaxf(m.z, f.z); m.w = fmaxf(m.w, f.w);
                any = 1;
            }
        }
    }

#pragma unroll
    for (int s = 8; s < 64; s <<= 1) {
        m.x = fmaxf(m.x, __shfl_xor(m.x, s, 64));
        m.y = fmaxf(m.y, __shfl_xor(m.y, s, 64));
        m.z = fmaxf(m.z, __shfl_xor(m.z, s, 64));
        m.w = fmaxf(m.w, __shfl_xor(m.w, s, 64));
    }
    bool active = (__ballot(any) != 0ULL);

    if (q == 0) {
        float4 z4 = make_float4(0.f, 0.f, 0.f, 0.f);
        out4[wid * (NC / 4) + cq] = active ? m : z4;
    }
}

// ---------------- launch ----------------

extern "C" void kernel_launch(void* const* d_in, const int* in_sizes, int n_in,
                              void* d_out, int out_size, void* d_ws, size_t ws_size,
                              hipStream_t stream) {
    const float* feat  = (const float*)d_in[0];
    const int*   coors = (const int*)d_in[1];
    const int N = in_sizes[0] / NC;          // 200000
    float* out = (float*)d_out;              // 1572864 floats

    const size_t fast_ints = (size_t)NBINS * LINE + 8 + 2ull * OVF_CAP;
    if (ws_size >= fast_ints * sizeof(int)) {
        int*  lines = (int*)d_ws;                       // NBINS*16
        int*  ovf_n = lines + NBINS * LINE;             // 1 (+7 pad)
        int2* ovf   = (int2*)(ovf_n + 8);               // OVF_CAP int2

        k_zero<<<(NBINS + 255) / 256, 256, 0, stream>>>(lines, ovf_n);
        k_bin<<<(N + 255) / 256, 256, 0, stream>>>(coors, lines, ovf_n, ovf, N);
        k_tile<<<NTILES, 512, 0, stream>>>(feat, lines, ovf_n, (const int2*)ovf,
                                           (float4*)out);
    } else {
        // fallback: scan-based path, ~1.6 MB ws
        int*  counts  = (int*)d_ws;
        int2* binfo   = (int2*)(counts + NBINS);
        int*  cursor  = (int*)(binfo + NBINS);
        int*  records = cursor + NBINS;

        hipMemsetAsync(counts, 0, NBINS * sizeof(int), stream);
        k_hist <<<(N + 255) / 256, 256, 0, stream>>>(coors, counts, N);
        k_scan <<<1, SCAN_T, 0, stream>>>(counts, binfo, cursor);
        k_place<<<(N + 255) / 256, 256, 0, stream>>>(coors, cursor, records, N);
        k_gather_fb<<<(NBINS * 64) / 256, 256, 0, stream>>>(
            (const float4*)feat, (const int2*)binfo, records, (float4*)out, N);
    }
}

// Round 9
// 43.244 us; speedup vs baseline: 2.9115x; 1.0062x over previous
//
#include <hip/hip_runtime.h>
#include <cfloat>
#include <cstdint>

// Problem constants (SHAPE=(96,128,128), B=2, C=32, two maxpool(K3,S2,P1) layers)
// Composed pooling: window 7, stride 4, pad 3. Output grid 2 x 24 x 32 x 32 x 32.
#define B_    2
#define OD    24
#define OH    32
#define OW    32
#define NC    32
#define NBINS (B_ * OD * OH * OW)   // 49152
#define RSTRIDE 16                  // record slots per bin (separate from counts)
#define OVF_CAP 100000
#define SCAN_T 1024
#define CHUNK  (NBINS / SCAN_T)

// tile geometry: 4 x 4 x 4 output cells per workgroup
#define TZ 4
#define TY 4
#define TX 4
#define TCELLS (TZ*TY*TX)           // 64
#define NTZ (OD/TZ)                 // 6
#define NTY (OH/TY)                 // 8
#define NTX (OW/TX)                 // 8
#define NTILES (B_*NTZ*NTY*NTX)     // 768 = 3 blocks/CU exactly
#define NBZ (TZ+1)
#define NBY (TY+1)
#define NBX (TX+1)
#define NB  (NBZ*NBY*NBX)           // 125 bins per tile neighborhood
#define LIST_CAP 1792               // avg entries/tile ~437

// ---------------- monotone float<->uint transform ----------------
// order-preserving for non-NaN floats; 0 == "never touched" (xform(f)>0 for all finite f)
__device__ __forceinline__ unsigned xform(float f) {
    unsigned u = __float_as_uint(f);
    return u ^ ((unsigned)((int)u >> 31) | 0x80000000u);
}
__device__ __forceinline__ float unxform(unsigned t) {
    return (t == 0u) ? 0.0f
           : __uint_as_float((t >> 31) ? (t ^ 0x80000000u) : ~t);
}

// ---------------- binning (counts compact + records stride-16) ----------------

__global__ __launch_bounds__(256) void k_bin(const int* __restrict__ coors,
                                             int* __restrict__ counts,
                                             int* __restrict__ records,
                                             int* __restrict__ ovf_n,
                                             int2* __restrict__ ovf, int N) {
    int i = blockIdx.x * blockDim.x + threadIdx.x;
    if (i >= N) return;
    int4 cc = reinterpret_cast<const int4*>(coors)[i];   // b, z, y, x
    int bin = (((cc.x * OD + (cc.y >> 2)) * OH + (cc.z >> 2)) * OW + (cc.w >> 2));
    // bit k (k = lz + 2*ly + 4*lx): point qualifies for cell bin+(lz,ly,lx)
    int mask = 0xFF;
    if (!(cc.y & 3)) mask &= 0x55;
    if (!(cc.z & 3)) mask &= 0x33;
    if (!(cc.w & 3)) mask &= 0x0F;
    int rec = (i << 8) | mask;   // mask bit0 always set -> rec != 0
    int pos = atomicAdd(&counts[bin], 1);
    if (pos < RSTRIDE) {
        records[bin * RSTRIDE + pos] = rec;
    } else {
        int o = atomicAdd(ovf_n, 1);
        if (o < OVF_CAP) ovf[o] = make_int2(bin, rec);
    }
}

// ---------------- tile gather-scatter ----------------
// one block per 4x4x4-cell tile; thread = (slot s = tid>>5 of 16, channel c = tid&31)

__global__ __launch_bounds__(512) void k_tile(const float* __restrict__ feat,
                                              const int* __restrict__ counts,
                                              const int* __restrict__ records,
                                              const int* __restrict__ ovf_n,
                                              const int2* __restrict__ ovf,
                                              float4* __restrict__ out4) {
    __shared__ unsigned sm_out[TCELLS * NC];   // 8 KB
    __shared__ int2 list[LIST_CAP];            // 14 KB
    __shared__ int sm_cursor;

    // XCD-aware swizzle: 768 % 8 == 0 -> bijective; each XCD owns a
    // contiguous spatial slab so its feat/lines working set is L2-resident.
    const int t   = (blockIdx.x & 7) * (NTILES / 8) + (blockIdx.x >> 3);
    const int tid = threadIdx.x;
    const int tx_ = t & (NTX - 1);
    const int ty_ = (t >> 3) & (NTY - 1);
    const int rest = t >> 6;                   // b*NTZ + tz, 0..11
    const int b   = (rest >= NTZ) ? 1 : 0;
    const int tz_ = rest - b * NTZ;
    const int tz0 = tz_ * TZ, ty0 = ty_ * TY, tx0 = tx_ * TX;

    if (tid == 0) sm_cursor = 0;
    for (int v = tid; v < TCELLS * NC; v += 512) sm_out[v] = 0u;
    __syncthreads();

    // ---- build compact entry list: TWO threads per neighborhood bin ----
    if (tid < 2 * NB) {
        int bn  = tid >> 1;                    // bin index 0..124
        int par = tid & 1;                     // slot parity
        int rz  = bn / (NBY * NBX);
        int rem = bn - rz * (NBY * NBX);
        int ry  = rem / NBX;
        int rx  = rem - ry * NBX;
        int bz = tz0 - 1 + rz, by = ty0 - 1 + ry, bx = tx0 - 1 + rx;
        if ((bz | by | bx) >= 0) {             // upper side in-grid by tiling
            int bin = ((b * OD + bz) * OH + by) * OW + bx;
            int cnt = counts[bin]; if (cnt > RSTRIDE) cnt = RSTRIDE;
            const int4* lp = (const int4*)(records + bin * RSTRIDE);
            int rbuf[16];
            *(int4*)&rbuf[0]  = lp[0]; *(int4*)&rbuf[4]  = lp[1];
            *(int4*)&rbuf[8]  = lp[2]; *(int4*)&rbuf[12] = lp[3];
            int bi = rz - 1, bj = ry - 1, bl = rx - 1;
            int vm = 0xFF;                     // tile-validity mask per k
            if (bi < 0) vm &= 0xAA;  if (bi > TZ - 2) vm &= 0x55;
            if (bj < 0) vm &= 0xCC;  if (bj > TY - 2) vm &= 0x33;
            if (bl < 0) vm &= 0xF0;  if (bl > TX - 2) vm &= 0x0F;
            int cb = bi * (TY * TX) + bj * TX + bl;
            // pass 1: count this parity's survivors
            int nk = 0;
#pragma unroll
            for (int rs = 0; rs < RSTRIDE; ++rs)
                if ((rs & 1) == par && rs < cnt && (rbuf[rs] & vm & 0xFF)) ++nk;
            int pos = atomicAdd(&sm_cursor, nk);
            // pass 2: write
#pragma unroll
            for (int rs = 0; rs < RSTRIDE; ++rs) {
                if ((rs & 1) == par && rs < cnt) {
                    int rec = rbuf[rs];
                    int fm = rec & vm & 0xFF;
                    if (fm) {
                        if (pos < LIST_CAP) {
                            list[pos] = make_int2((rec & ~0xFF) | fm, cb);
                        } else {
                            // never-taken slow path: apply directly
                            unsigned idx = ((unsigned)rec) >> 8;
                            for (int c2 = 0; c2 < NC; ++c2) {
                                unsigned tvv = xform(feat[idx * NC + c2]);
#pragma unroll
                                for (int k = 0; k < 8; ++k) {
                                    const int koff = ((k & 1) * (TY * TX)
                                        + ((k >> 1) & 1) * TX + ((k >> 2) & 1)) * NC;
                                    if ((fm >> k) & 1)
                                        atomicMax(&sm_out[(cb * NC) + koff + c2], tvv);
                                }
                            }
                        }
                        ++pos;
                    }
                }
            }
        }
    }

    // ---- overflow net (expected empty) ----
    int on = *ovf_n;
    if (on > 0 && tid == 0) {
        if (on > OVF_CAP) on = OVF_CAP;
        for (int e = 0; e < on; ++e) {
            int2 ov = ovf[e];
            int bx = ov.x & (OW - 1);
            int by = (ov.x >> 5) & (OH - 1);
            int rest2 = ov.x >> 10;            // b*OD + bz
            int bb = (rest2 >= OD) ? 1 : 0;
            int bz = rest2 - bb * OD;
            if (bb != b) continue;
            int rz = bz - (tz0 - 1), ry = by - (ty0 - 1), rx = bx - (tx0 - 1);
            if (rz < 0 || rz >= NBZ || ry < 0 || ry >= NBY || rx < 0 || rx >= NBX) continue;
            int bi = rz - 1, bj = ry - 1, bl = rx - 1;
            int vm = 0xFF;
            if (bi < 0) vm &= 0xAA;  if (bi > TZ - 2) vm &= 0x55;
            if (bj < 0) vm &= 0xCC;  if (bj > TY - 2) vm &= 0x33;
            if (bl < 0) vm &= 0xF0;  if (bl > TX - 2) vm &= 0x0F;
            int fm = ov.y & vm & 0xFF;
            if (fm) {
                int pos = atomicAdd(&sm_cursor, 1);
                if (pos < LIST_CAP)
                    list[pos] = make_int2((ov.y & ~0xFF) | fm,
                                          bi * (TY * TX) + bj * TX + bl);
            }
        }
    }
    __syncthreads();
    int total = sm_cursor; if (total > LIST_CAP) total = LIST_CAP;

    // ---- main loop: 16 slots x 8-deep ILP = 128 entries per round ----
    const int s = tid >> 5;
    const int c = tid & 31;

    for (int j0 = s; j0 < total; j0 += 128) {
        int2 e[8];
        unsigned tv[8];
#pragma unroll
        for (int u = 0; u < 8; ++u) {
            int j = j0 + 16 * u;
            e[u] = (j < total) ? list[j] : make_int2(0, 0);   // fm=0 -> no-op
        }
#pragma unroll
        for (int u = 0; u < 8; ++u)
            tv[u] = xform(feat[(((unsigned)e[u].x) >> 8) * NC + c]);
#pragma unroll
        for (int u = 0; u < 8; ++u) {
#pragma unroll
            for (int k = 0; k < 8; ++k) {
                const int koff = ((k & 1) * (TY * TX) + ((k >> 1) & 1) * TX
                               + ((k >> 2) & 1)) * NC + c;
                if ((e[u].x >> k) & 1) atomicMax(&sm_out[e[u].y * NC + koff], tv[u]);
            }
        }
    }
    __syncthreads();

    // ---- epilogue: 64 cells x 8 float4 = 512 stores, one per thread ----
    {
        const int cell = tid >> 3, quad = tid & 7;
        const int i = cell >> 4, jj = (cell >> 2) & 3, l = cell & 3;
        uint4 uv = *(const uint4*)&sm_out[cell * NC + quad * 4];
        float4 o;
        o.x = unxform(uv.x); o.y = unxform(uv.y);
        o.z = unxform(uv.z); o.w = unxform(uv.w);
        out4[(((size_t)(b * OD + tz0 + i) * OH + (ty0 + jj)) * OW
              + (tx0 + l)) * (NC / 4) + quad] = o;
    }
}

// ================= fallback path (scan-based, small ws) =====================

__global__ void k_hist(const int* __restrict__ coors, int* __restrict__ counts, int N) {
    int i = blockIdx.x * blockDim.x + threadIdx.x;
    if (i >= N) return;
    int4 cc = reinterpret_cast<const int4*>(coors)[i];
    int bin = (((cc.x * OD + (cc.y >> 2)) * OH + (cc.z >> 2)) * OW + (cc.w >> 2));
    atomicAdd(&counts[bin], 1);
}

__global__ void k_scan(const int* __restrict__ counts,
                       int2* __restrict__ binfo,
                       int* __restrict__ cursor) {
    __shared__ int lds[SCAN_T];
    int t = threadIdx.x;
    int base = t * CHUNK;
    int s = 0;
#pragma unroll
    for (int k = 0; k < CHUNK; ++k) s += counts[base + k];
    lds[t] = s;
    __syncthreads();
    for (int d = 1; d < SCAN_T; d <<= 1) {
        int v = (t >= d) ? lds[t - d] : 0;
        __syncthreads();
        lds[t] += v;
        __syncthreads();
    }
    int excl = (t == 0) ? 0 : lds[t - 1];
    for (int k = 0; k < CHUNK; ++k) {
        int i = base + k;
        int c = counts[i];
        binfo[i] = make_int2(excl, c);
        cursor[i] = excl;
        excl += c;
    }
}

__global__ void k_place(const int* __restrict__ coors, int* __restrict__ cursor,
                        int* __restrict__ records, int N) {
    int i = blockIdx.x * blockDim.x + threadIdx.x;
    if (i >= N) return;
    int4 cc = reinterpret_cast<const int4*>(coors)[i];
    int bin = (((cc.x * OD + (cc.y >> 2)) * OH + (cc.z >> 2)) * OW + (cc.w >> 2));
    int pos = atomicAdd(&cursor[bin], 1);
    records[pos] = (i << 6) | (cc.y & 3) | ((cc.z & 3) << 2) | ((cc.w & 3) << 4);
}

__global__ __launch_bounds__(256) void k_gather_fb(const float4* __restrict__ feat4,
                                                   const int2* __restrict__ binfo,
                                                   const int* __restrict__ records,
                                                   float4* __restrict__ out4, int N) {
    int tid  = blockIdx.x * blockDim.x + threadIdx.x;
    int wid  = tid >> 6;
    int lane = threadIdx.x & 63;
    int q    = lane >> 3;
    int cq   = lane & 7;

    int ox  = wid & (OW - 1);
    int oy  = (wid >> 5) & (OH - 1);
    int bzc = wid >> 10;
    int b   = (bzc >= OD) ? 1 : 0;
    int oz  = bzc - b * OD;

    int2 bi[8];
#pragma unroll
    for (int k = 0; k < 8; ++k) {
        const int lz = k & 1, ly = (k >> 1) & 1, lx = (k >> 2) & 1;
        int z2 = oz - lz, y2 = oy - ly, x2 = ox - lx;
        bool okbin = ((z2 | y2 | x2) >= 0);
        int bin = ((b * OD + z2) * OH + y2) * OW + x2;
        int2 v = binfo[okbin ? bin : 0];
        if (!okbin) { v.x = N; v.y = 0; }
        bi[k] = v;
    }

    int recs[8];
#pragma unroll
    for (int k = 0; k < 8; ++k) {
        int j = (q < bi[k].y) ? q : 0;
        recs[k] = records[bi[k].x + j];
    }

    float4 m = make_float4(-FLT_MAX, -FLT_MAX, -FLT_MAX, -FLT_MAX);
    int any = 0;
#pragma unroll
    for (int k = 0; k < 8; ++k) {
        int rec = recs[k];
        bool ok = (q < bi[k].y);
        if (k & 1) ok = ok && ((rec & 3)  != 0);
        if (k & 2) ok = ok && ((rec & 12) != 0);
        if (k & 4) ok = ok && ((rec & 48) != 0);
        if (ok) {
            float4 f = feat4[(rec >> 6) * (NC / 4) + cq];
            m.x = fmaxf(m.x, f.x); m.y = fmaxf(m.y, f.y);
            m.z = fmaxf(m.z, f.z); m.w = fmaxf(m.w, f.w);
            any = 1;
        }
    }

#pragma unroll
    for (int k = 0; k < 8; ++k) {
        for (int j0 = 8; j0 < bi[k].y; j0 += 8) {
            int j = j0 + q;
            bool ok = (j < bi[k].y);
            int rec = records[bi[k].x + (ok ? j : 0)];
            if (k & 1) ok = ok && ((rec & 3)  != 0);
            if (k & 2) ok = ok && ((rec & 12) != 0);
            if (k & 4) ok = ok && ((rec & 48) != 0);
            if (ok) {
                float4 f = feat4[(rec >> 6) * (NC / 4) + cq];
                m.x = fmaxf(m.x, f.x); m.y = fmaxf(m.y, f.y);
                m.z = fmaxf(m.z, f.z); m.w = fmaxf(m.w, f.w);
                any = 1;
            }
        }
    }

#pragma unroll
    for (int s = 8; s < 64; s <<= 1) {
        m.x = fmaxf(m.x, __shfl_xor(m.x, s, 64));
        m.y = fmaxf(m.y, __shfl_xor(m.y, s, 64));
        m.z = fmaxf(m.z, __shfl_xor(m.z, s, 64));
        m.w = fmaxf(m.w, __shfl_xor(m.w, s, 64));
    }
    bool active = (__ballot(any) != 0ULL);

    if (q == 0) {
        float4 z4 = make_float4(0.f, 0.f, 0.f, 0.f);
        out4[wid * (NC / 4) + cq] = active ? m : z4;
    }
}

// ---------------- launch ----------------

extern "C" void kernel_launch(void* const* d_in, const int* in_sizes, int n_in,
                              void* d_out, int out_size, void* d_ws, size_t ws_size,
                              hipStream_t stream) {
    const float* feat  = (const float*)d_in[0];
    const int*   coors = (const int*)d_in[1];
    const int N = in_sizes[0] / NC;          // 200000
    float* out = (float*)d_out;              // 1572864 floats

    const size_t fast_ints = (size_t)NBINS + 8 + (size_t)NBINS * RSTRIDE
                           + 2ull * OVF_CAP;
    if (ws_size >= fast_ints * sizeof(int)) {
        int*  counts  = (int*)d_ws;                     // NBINS
        int*  ovf_n   = counts + NBINS;                 // 1 (+7 pad)
        int*  records = counts + NBINS + 8;             // NBINS*16
        int2* ovf     = (int2*)(records + (size_t)NBINS * RSTRIDE);

        hipMemsetAsync(counts, 0, (NBINS + 8) * sizeof(int), stream);
        k_bin<<<(N + 255) / 256, 256, 0, stream>>>(coors, counts, records,
                                                   ovf_n, ovf, N);
        k_tile<<<NTILES, 512, 0, stream>>>(feat, counts, records,
                                           ovf_n, (const int2*)ovf, (float4*)out);
    } else {
        // fallback: scan-based path, ~1.6 MB ws
        int*  counts  = (int*)d_ws;
        int2* binfo   = (int2*)(counts + NBINS);
        int*  cursor  = (int*)(binfo + NBINS);
        int*  records = cursor + NBINS;

        hipMemsetAsync(counts, 0, NBINS * sizeof(int), stream);
        k_hist <<<(N + 255) / 256, 256, 0, stream>>>(coors, counts, N);
        k_scan <<<1, SCAN_T, 0, stream>>>(counts, binfo, cursor);
        k_place<<<(N + 255) / 256, 256, 0, stream>>>(coors, cursor, records, N);
        k_gather_fb<<<(NBINS * 64) / 256, 256, 0, stream>>>(
            (const float4*)feat, (const int2*)binfo, records, (float4*)out, N);
    }
}

// Round 10
// 41.264 us; speedup vs baseline: 3.0512x; 1.0480x over previous
//
#include <hip/hip_runtime.h>
#include <cfloat>
#include <cstdint>

// Problem constants (SHAPE=(96,128,128), B=2, C=32, two maxpool(K3,S2,P1) layers)
// Composed pooling: window 7, stride 4, pad 3. Output grid 2 x 24 x 32 x 32 x 32.
#define B_    2
#define OD    24
#define OH    32
#define OW    32
#define NC    32
#define NBINS (B_ * OD * OH * OW)   // 49152
#define RSTRIDE 16                  // record slots per bin (separate from counts)
#define OVF_CAP 100000
#define SCAN_T 1024
#define CHUNK  (NBINS / SCAN_T)

// tile geometry: 4 x 4 x 4 output cells per workgroup
#define TZ 4
#define TY 4
#define TX 4
#define TCELLS (TZ*TY*TX)           // 64
#define NTZ (OD/TZ)                 // 6
#define NTY (OH/TY)                 // 8
#define NTX (OW/TX)                 // 8
#define NTILES (B_*NTZ*NTY*NTX)     // 768 = 3 blocks/CU exactly
#define NBZ (TZ+1)
#define NBY (TY+1)
#define NBX (TX+1)
#define NB  (NBZ*NBY*NBX)           // 125 bins per tile neighborhood
#define LIST_CAP 1792               // avg entries/tile ~437

// ---------------- monotone float<->uint transform ----------------
// order-preserving for non-NaN floats; 0 == "never touched" (xform(f)>0 for all finite f)
__device__ __forceinline__ unsigned xform(float f) {
    unsigned u = __float_as_uint(f);
    return u ^ ((unsigned)((int)u >> 31) | 0x80000000u);
}
__device__ __forceinline__ float unxform(unsigned t) {
    return (t == 0u) ? 0.0f
           : __uint_as_float((t >> 31) ? (t ^ 0x80000000u) : ~t);
}

// rare slow path: apply one record directly to the LDS accumulator
__device__ __forceinline__ void slow_apply(unsigned* sm_out, const float* feat,
                                           int rec, int fm, int cb) {
    unsigned idx = ((unsigned)rec) >> 8;
    for (int c2 = 0; c2 < NC; ++c2) {
        unsigned tvv = xform(feat[idx * NC + c2]);
#pragma unroll
        for (int k = 0; k < 8; ++k) {
            const int koff = ((k & 1) * (TY * TX) + ((k >> 1) & 1) * TX
                           + ((k >> 2) & 1)) * NC;
            if ((fm >> k) & 1) atomicMax(&sm_out[cb * NC + koff + c2], tvv);
        }
    }
}

// ---------------- binning (counts compact + records stride-16) ----------------

__global__ __launch_bounds__(256) void k_bin(const int* __restrict__ coors,
                                             int* __restrict__ counts,
                                             int* __restrict__ records,
                                             int* __restrict__ ovf_n,
                                             int2* __restrict__ ovf, int N) {
    int i = blockIdx.x * blockDim.x + threadIdx.x;
    if (i >= N) return;
    int4 cc = reinterpret_cast<const int4*>(coors)[i];   // b, z, y, x
    int bin = (((cc.x * OD + (cc.y >> 2)) * OH + (cc.z >> 2)) * OW + (cc.w >> 2));
    // bit k (k = lz + 2*ly + 4*lx): point qualifies for cell bin+(lz,ly,lx)
    int mask = 0xFF;
    if (!(cc.y & 3)) mask &= 0x55;
    if (!(cc.z & 3)) mask &= 0x33;
    if (!(cc.w & 3)) mask &= 0x0F;
    int rec = (i << 8) | mask;   // mask bit0 always set -> rec != 0
    int pos = atomicAdd(&counts[bin], 1);
    if (pos < RSTRIDE) {
        records[bin * RSTRIDE + pos] = rec;
    } else {
        int o = atomicAdd(ovf_n, 1);
        if (o < OVF_CAP) ovf[o] = make_int2(bin, rec);
    }
}

// ---------------- tile gather-scatter ----------------
// one block per 4x4x4-cell tile; thread = (slot s = tid>>5 of 16, channel c = tid&31)

__global__ __launch_bounds__(512) void k_tile(const float* __restrict__ feat,
                                              const int* __restrict__ counts,
                                              const int* __restrict__ records,
                                              const int* __restrict__ ovf_n,
                                              const int2* __restrict__ ovf,
                                              float4* __restrict__ out4) {
    __shared__ unsigned sm_out[TCELLS * NC];   // 8 KB
    __shared__ int2 list[LIST_CAP];            // 14 KB
    __shared__ int sm_cursor;

    // XCD-aware swizzle: 768 % 8 == 0 -> bijective; each XCD owns a
    // contiguous spatial slab so its feat/records working set is L2-resident.
    const int t   = (blockIdx.x & 7) * (NTILES / 8) + (blockIdx.x >> 3);
    const int tid = threadIdx.x;
    const int tx_ = t & (NTX - 1);
    const int ty_ = (t >> 3) & (NTY - 1);
    const int rest = t >> 6;                   // b*NTZ + tz, 0..11
    const int b   = (rest >= NTZ) ? 1 : 0;
    const int tz_ = rest - b * NTZ;
    const int tz0 = tz_ * TZ, ty0 = ty_ * TY, tx0 = tx_ * TX;

    if (tid == 0) sm_cursor = 0;
    for (int v = tid; v < TCELLS * NC; v += 512) sm_out[v] = 0u;
    __syncthreads();

    // ---- build compact entry list: FOUR threads per neighborhood bin ----
    // thread = (bin bn = tid>>2, int4-slot sl = tid&3); NO addressable locals:
    // the 4 records live in a named int4 register, components picked at
    // compile time (avoids SROA failure -> scratch serialization).
    if (tid < 4 * NB) {                        // 500 threads, all 8 waves
        int bn  = tid >> 2;                    // bin index 0..124
        int sl  = tid & 3;                     // record quad 0..3
        int rz  = bn / (NBY * NBX);
        int rem = bn - rz * (NBY * NBX);
        int ry  = rem / NBX;
        int rx  = rem - ry * NBX;
        int bz = tz0 - 1 + rz, by = ty0 - 1 + ry, bx = tx0 - 1 + rx;
        if ((bz | by | bx) >= 0) {             // upper side in-grid by tiling
            int bin = ((b * OD + bz) * OH + by) * OW + bx;
            int cnt = counts[bin]; if (cnt > RSTRIDE) cnt = RSTRIDE;
            int4 q = *(const int4*)(records + bin * RSTRIDE + sl * 4);
            int bi = rz - 1, bj = ry - 1, bl = rx - 1;
            int vm = 0xFF;                     // tile-validity mask per k
            if (bi < 0) vm &= 0xAA;  if (bi > TZ - 2) vm &= 0x55;
            if (bj < 0) vm &= 0xCC;  if (bj > TY - 2) vm &= 0x33;
            if (bl < 0) vm &= 0xF0;  if (bl > TX - 2) vm &= 0x0F;
            int cb = bi * (TY * TX) + bj * TX + bl;
            int rs0 = sl << 2;
            int f0 = (rs0 + 0 < cnt) ? (q.x & vm & 0xFF) : 0;
            int f1 = (rs0 + 1 < cnt) ? (q.y & vm & 0xFF) : 0;
            int f2 = (rs0 + 2 < cnt) ? (q.z & vm & 0xFF) : 0;
            int f3 = (rs0 + 3 < cnt) ? (q.w & vm & 0xFF) : 0;
            int nk = (f0 != 0) + (f1 != 0) + (f2 != 0) + (f3 != 0);
            if (nk) {
                int pos = atomicAdd(&sm_cursor, nk);
                if (f0) { if (pos < LIST_CAP) list[pos] = make_int2((q.x & ~0xFF) | f0, cb);
                          else slow_apply(sm_out, feat, q.x, f0, cb); ++pos; }
                if (f1) { if (pos < LIST_CAP) list[pos] = make_int2((q.y & ~0xFF) | f1, cb);
                          else slow_apply(sm_out, feat, q.y, f1, cb); ++pos; }
                if (f2) { if (pos < LIST_CAP) list[pos] = make_int2((q.z & ~0xFF) | f2, cb);
                          else slow_apply(sm_out, feat, q.z, f2, cb); ++pos; }
                if (f3) { if (pos < LIST_CAP) list[pos] = make_int2((q.w & ~0xFF) | f3, cb);
                          else slow_apply(sm_out, feat, q.w, f3, cb); ++pos; }
            }
        }
    }

    // ---- overflow net (expected empty) ----
    int on = *ovf_n;
    if (on > 0 && tid == 0) {
        if (on > OVF_CAP) on = OVF_CAP;
        for (int e = 0; e < on; ++e) {
            int2 ov = ovf[e];
            int bx = ov.x & (OW - 1);
            int by = (ov.x >> 5) & (OH - 1);
            int rest2 = ov.x >> 10;            // b*OD + bz
            int bb = (rest2 >= OD) ? 1 : 0;
            int bz = rest2 - bb * OD;
            if (bb != b) continue;
            int rz = bz - (tz0 - 1), ry = by - (ty0 - 1), rx = bx - (tx0 - 1);
            if (rz < 0 || rz >= NBZ || ry < 0 || ry >= NBY || rx < 0 || rx >= NBX) continue;
            int bi = rz - 1, bj = ry - 1, bl = rx - 1;
            int vm = 0xFF;
            if (bi < 0) vm &= 0xAA;  if (bi > TZ - 2) vm &= 0x55;
            if (bj < 0) vm &= 0xCC;  if (bj > TY - 2) vm &= 0x33;
            if (bl < 0) vm &= 0xF0;  if (bl > TX - 2) vm &= 0x0F;
            int fm = ov.y & vm & 0xFF;
            if (fm) {
                int pos = atomicAdd(&sm_cursor, 1);
                if (pos < LIST_CAP)
                    list[pos] = make_int2((ov.y & ~0xFF) | fm,
                                          bi * (TY * TX) + bj * TX + bl);
            }
        }
    }
    __syncthreads();
    int total = sm_cursor; if (total > LIST_CAP) total = LIST_CAP;

    // ---- main loop: 16 slots x 8-deep ILP = 128 entries per round ----
    const int s = tid >> 5;
    const int c = tid & 31;

    for (int j0 = s; j0 < total; j0 += 128) {
        int2 e[8];
        unsigned tv[8];
#pragma unroll
        for (int u = 0; u < 8; ++u) {
            int j = j0 + 16 * u;
            e[u] = (j < total) ? list[j] : make_int2(0, 0);   // fm=0 -> no-op
        }
#pragma unroll
        for (int u = 0; u < 8; ++u)
            tv[u] = xform(feat[(((unsigned)e[u].x) >> 8) * NC + c]);
#pragma unroll
        for (int u = 0; u < 8; ++u) {
#pragma unroll
            for (int k = 0; k < 8; ++k) {
                const int koff = ((k & 1) * (TY * TX) + ((k >> 1) & 1) * TX
                               + ((k >> 2) & 1)) * NC + c;
                if ((e[u].x >> k) & 1) atomicMax(&sm_out[e[u].y * NC + koff], tv[u]);
            }
        }
    }
    __syncthreads();

    // ---- epilogue: 64 cells x 8 float4 = 512 stores, one per thread ----
    {
        const int cell = tid >> 3, quad = tid & 7;
        const int i = cell >> 4, jj = (cell >> 2) & 3, l = cell & 3;
        uint4 uv = *(const uint4*)&sm_out[cell * NC + quad * 4];
        float4 o;
        o.x = unxform(uv.x); o.y = unxform(uv.y);
        o.z = unxform(uv.z); o.w = unxform(uv.w);
        out4[(((size_t)(b * OD + tz0 + i) * OH + (ty0 + jj)) * OW
              + (tx0 + l)) * (NC / 4) + quad] = o;
    }
}

// ================= fallback path (scan-based, small ws) =====================

__global__ void k_hist(const int* __restrict__ coors, int* __restrict__ counts, int N) {
    int i = blockIdx.x * blockDim.x + threadIdx.x;
    if (i >= N) return;
    int4 cc = reinterpret_cast<const int4*>(coors)[i];
    int bin = (((cc.x * OD + (cc.y >> 2)) * OH + (cc.z >> 2)) * OW + (cc.w >> 2));
    atomicAdd(&counts[bin], 1);
}

__global__ void k_scan(const int* __restrict__ counts,
                       int2* __restrict__ binfo,
                       int* __restrict__ cursor) {
    __shared__ int lds[SCAN_T];
    int t = threadIdx.x;
    int base = t * CHUNK;
    int s = 0;
#pragma unroll
    for (int k = 0; k < CHUNK; ++k) s += counts[base + k];
    lds[t] = s;
    __syncthreads();
    for (int d = 1; d < SCAN_T; d <<= 1) {
        int v = (t >= d) ? lds[t - d] : 0;
        __syncthreads();
        lds[t] += v;
        __syncthreads();
    }
    int excl = (t == 0) ? 0 : lds[t - 1];
    for (int k = 0; k < CHUNK; ++k) {
        int i = base + k;
        int c = counts[i];
        binfo[i] = make_int2(excl, c);
        cursor[i] = excl;
        excl += c;
    }
}

__global__ void k_place(const int* __restrict__ coors, int* __restrict__ cursor,
                        int* __restrict__ records, int N) {
    int i = blockIdx.x * blockDim.x + threadIdx.x;
    if (i >= N) return;
    int4 cc = reinterpret_cast<const int4*>(coors)[i];
    int bin = (((cc.x * OD + (cc.y >> 2)) * OH + (cc.z >> 2)) * OW + (cc.w >> 2));
    int pos = atomicAdd(&cursor[bin], 1);
    records[pos] = (i << 6) | (cc.y & 3) | ((cc.z & 3) << 2) | ((cc.w & 3) << 4);
}

__global__ __launch_bounds__(256) void k_gather_fb(const float4* __restrict__ feat4,
                                                   const int2* __restrict__ binfo,
                                                   const int* __restrict__ records,
                                                   float4* __restrict__ out4, int N) {
    int tid  = blockIdx.x * blockDim.x + threadIdx.x;
    int wid  = tid >> 6;
    int lane = threadIdx.x & 63;
    int q    = lane >> 3;
    int cq   = lane & 7;

    int ox  = wid & (OW - 1);
    int oy  = (wid >> 5) & (OH - 1);
    int bzc = wid >> 10;
    int b   = (bzc >= OD) ? 1 : 0;
    int oz  = bzc - b * OD;

    int2 bi[8];
#pragma unroll
    for (int k = 0; k < 8; ++k) {
        const int lz = k & 1, ly = (k >> 1) & 1, lx = (k >> 2) & 1;
        int z2 = oz - lz, y2 = oy - ly, x2 = ox - lx;
        bool okbin = ((z2 | y2 | x2) >= 0);
        int bin = ((b * OD + z2) * OH + y2) * OW + x2;
        int2 v = binfo[okbin ? bin : 0];
        if (!okbin) { v.x = N; v.y = 0; }
        bi[k] = v;
    }

    int recs[8];
#pragma unroll
    for (int k = 0; k < 8; ++k) {
        int j = (q < bi[k].y) ? q : 0;
        recs[k] = records[bi[k].x + j];
    }

    float4 m = make_float4(-FLT_MAX, -FLT_MAX, -FLT_MAX, -FLT_MAX);
    int any = 0;
#pragma unroll
    for (int k = 0; k < 8; ++k) {
        int rec = recs[k];
        bool ok = (q < bi[k].y);
        if (k & 1) ok = ok && ((rec & 3)  != 0);
        if (k & 2) ok = ok && ((rec & 12) != 0);
        if (k & 4) ok = ok && ((rec & 48) != 0);
        if (ok) {
            float4 f = feat4[(rec >> 6) * (NC / 4) + cq];
            m.x = fmaxf(m.x, f.x); m.y = fmaxf(m.y, f.y);
            m.z = fmaxf(m.z, f.z); m.w = fmaxf(m.w, f.w);
            any = 1;
        }
    }

#pragma unroll
    for (int k = 0; k < 8; ++k) {
        for (int j0 = 8; j0 < bi[k].y; j0 += 8) {
            int j = j0 + q;
            bool ok = (j < bi[k].y);
            int rec = records[bi[k].x + (ok ? j : 0)];
            if (k & 1) ok = ok && ((rec & 3)  != 0);
            if (k & 2) ok = ok && ((rec & 12) != 0);
            if (k & 4) ok = ok && ((rec & 48) != 0);
            if (ok) {
                float4 f = feat4[(rec >> 6) * (NC / 4) + cq];
                m.x = fmaxf(m.x, f.x); m.y = fmaxf(m.y, f.y);
                m.z = fmaxf(m.z, f.z); m.w = fmaxf(m.w, f.w);
                any = 1;
            }
        }
    }

#pragma unroll
    for (int s = 8; s < 64; s <<= 1) {
        m.x = fmaxf(m.x, __shfl_xor(m.x, s, 64));
        m.y = fmaxf(m.y, __shfl_xor(m.y, s, 64));
        m.z = fmaxf(m.z, __shfl_xor(m.z, s, 64));
        m.w = fmaxf(m.w, __shfl_xor(m.w, s, 64));
    }
    bool active = (__ballot(any) != 0ULL);

    if (q == 0) {
        float4 z4 = make_float4(0.f, 0.f, 0.f, 0.f);
        out4[wid * (NC / 4) + cq] = active ? m : z4;
    }
}

// ---------------- launch ----------------

extern "C" void kernel_launch(void* const* d_in, const int* in_sizes, int n_in,
                              void* d_out, int out_size, void* d_ws, size_t ws_size,
                              hipStream_t stream) {
    const float* feat  = (const float*)d_in[0];
    const int*   coors = (const int*)d_in[1];
    const int N = in_sizes[0] / NC;          // 200000
    float* out = (float*)d_out;              // 1572864 floats

    const size_t fast_ints = (size_t)NBINS + 8 + (size_t)NBINS * RSTRIDE
                           + 2ull * OVF_CAP;
    if (ws_size >= fast_ints * sizeof(int)) {
        int*  counts  = (int*)d_ws;                     // NBINS
        int*  ovf_n   = counts + NBINS;                 // 1 (+7 pad)
        int*  records = counts + NBINS + 8;             // NBINS*16
        int2* ovf     = (int2*)(records + (size_t)NBINS * RSTRIDE);

        hipMemsetAsync(counts, 0, (NBINS + 8) * sizeof(int), stream);
        k_bin<<<(N + 255) / 256, 256, 0, stream>>>(coors, counts, records,
                                                   ovf_n, ovf, N);
        k_tile<<<NTILES, 512, 0, stream>>>(feat, counts, records,
                                           ovf_n, (const int2*)ovf, (float4*)out);
    } else {
        // fallback: scan-based path, ~1.6 MB ws
        int*  counts  = (int*)d_ws;
        int2* binfo   = (int2*)(counts + NBINS);
        int*  cursor  = (int*)(binfo + NBINS);
        int*  records = cursor + NBINS;

        hipMemsetAsync(counts, 0, NBINS * sizeof(int), stream);
        k_hist <<<(N + 255) / 256, 256, 0, stream>>>(coors, counts, N);
        k_scan <<<1, SCAN_T, 0, stream>>>(counts, binfo, cursor);
        k_place<<<(N + 255) / 256, 256, 0, stream>>>(coors, cursor, records, N);
        k_gather_fb<<<(NBINS * 64) / 256, 256, 0, stream>>>(
            (const float4*)feat, (const int2*)binfo, records, (float4*)out, N);
    }
}